// Round 4
// baseline (77.863 us; speedup 1.0000x reference)
//
#include <hip/hip_runtime.h>
#include <hip/hip_bf16.h>

#define N_TOK 16384
#define B_DIM 8
#define C_DIM 256
#define M_ROWS (N_TOK * B_DIM)   // 131072
#define BM 64

typedef __attribute__((ext_vector_type(8))) short short8;
typedef __attribute__((ext_vector_type(4))) float f32x4;

__device__ __forceinline__ unsigned short f2bf(float f) {
    union { float f; unsigned u; } v; v.f = f;
    unsigned r = v.u + 0x7fffu + ((v.u >> 16) & 1u);  // RNE
    return (unsigned short)(r >> 16);
}

__device__ __forceinline__ float bf2f(unsigned short h) {
    union { unsigned u; float f; } v; v.u = ((unsigned)h) << 16;
    return v.f;
}

// packed RNE f32x2 -> bf16x2 (low = a, high = b)
__device__ __forceinline__ unsigned cvt_pk(float a, float b) {
    unsigned r;
    asm("v_cvt_pk_bf16_f32 %0, %1, %2" : "=v"(r) : "v"(a), "v"(b));
    return r;
}

// Kernel A: m = (fg_gt != 0) * (1 - mask^T) -> d_out tail; W fp32 -> bf16 ws.
__global__ __launch_bounds__(256)
void prep_kernel(const int* __restrict__ mask, const int* __restrict__ fg,
                 const float* __restrict__ W, unsigned short* __restrict__ Wbf,
                 float* __restrict__ m_out) {
    int i = blockIdx.x * 256 + threadIdx.x;
    if (i < C_DIM * C_DIM) Wbf[i] = f2bf(W[i]);
    if (i < M_ROWS) {
        int b = i & (B_DIM - 1);
        int n = i >> 3;
        m_out[i] = (fg[i] != 0) ? (1.0f - (float)mask[b * N_TOK + n]) : 0.0f;
    }
}

// Kernel B: one 64-row tile per block; bf16 x in LDS (exactly 32 KB);
// W frags from L2 with 1-deep prefetch; nontemporal output stores.
__global__ __launch_bounds__(256, 4)
void mlp_kernel(const float* __restrict__ x, const unsigned short* __restrict__ Wbf,
                const float* __restrict__ bias, const float* __restrict__ m,
                float* __restrict__ out) {
    __shared__ unsigned short lds_x[BM * C_DIM];  // exactly 32 KB, XOR-swizzled

    const int t    = threadIdx.x;
    const int row0 = blockIdx.x * BM;

    // ---- Stage x tile (64 x 256 fp32 -> bf16 LDS), coalesced 32B/lane ----
    #pragma unroll
    for (int j = 0; j < 8; ++j) {
        int ci  = j * 256 + t;
        int row = ci >> 5;            // 0..63
        int cc  = (ci & 31) * 8;      // 0..248
        const float4* p = (const float4*)(x + (size_t)(row0 + row) * C_DIM + cc);
        float4 a0 = p[0];
        float4 a1 = p[1];
        int4 pk;
        pk.x = (int)cvt_pk(a0.x, a0.y);
        pk.y = (int)cvt_pk(a0.z, a0.w);
        pk.z = (int)cvt_pk(a1.x, a1.y);
        pk.w = (int)cvt_pk(a1.z, a1.w);
        int byte = (row * 512 + cc * 2) ^ ((row & 7) << 4);
        *(int4*)((char*)lds_x + byte) = pk;
    }
    __syncthreads();

    // ---- MFMA main loop: 4 waves x 64 cols, 4x4 16x16 tiles ----
    const int lane = t & 63;
    const int wid  = t >> 6;
    const int col0 = wid * 64;
    const int lr   = lane & 15;
    const int kb   = (lane >> 4) * 8;
    const int rsub = (lane >> 4) * 4;   // C/D: row = (lane>>4)*4 + reg

    const unsigned short* wp[4];
    #pragma unroll
    for (int ct = 0; ct < 4; ++ct)
        wp[ct] = Wbf + (size_t)(col0 + ct * 16 + lr) * C_DIM + kb;

    f32x4 acc[4][4];
    #pragma unroll
    for (int i = 0; i < 4; ++i)
        #pragma unroll
        for (int j = 0; j < 4; ++j) acc[i][j] = (f32x4){0.f, 0.f, 0.f, 0.f};

    short8 bcur[4], bnext[4];
    #pragma unroll
    for (int ct = 0; ct < 4; ++ct) bcur[ct] = *(const short8*)(wp[ct]);

    #pragma unroll
    for (int k8 = 0; k8 < 8; ++k8) {
        if (k8 < 7) {
            #pragma unroll
            for (int ct = 0; ct < 4; ++ct)
                bnext[ct] = *(const short8*)(wp[ct] + (k8 + 1) * 32);
        }
        const int kk = k8 * 32;
        short8 af[4];
        #pragma unroll
        for (int rt = 0; rt < 4; ++rt) {
            int row  = rt * 16 + lr;
            int byte = (row * 512 + (kk + kb) * 2) ^ ((row & 7) << 4);
            af[rt] = *(const short8*)((const char*)lds_x + byte);
        }
        #pragma unroll
        for (int rt = 0; rt < 4; ++rt)
            #pragma unroll
            for (int ct = 0; ct < 4; ++ct)
                acc[rt][ct] = __builtin_amdgcn_mfma_f32_16x16x32_bf16(
                    af[rt], bcur[ct], acc[rt][ct], 0, 0, 0);
        #pragma unroll
        for (int ct = 0; ct < 4; ++ct) bcur[ct] = bnext[ct];
    }

    // ---- Epilogue: relu(acc+b), select vs x (bf16 from LDS), nt store ----
    float bv[4];
    #pragma unroll
    for (int ct = 0; ct < 4; ++ct) bv[ct] = bias[col0 + ct * 16 + lr];

    float4 mreg[4];
    #pragma unroll
    for (int rt = 0; rt < 4; ++rt)
        mreg[rt] = *(const float4*)(m + row0 + rt * 16 + rsub);

    #pragma unroll
    for (int rt = 0; rt < 4; ++rt) {
        #pragma unroll
        for (int r = 0; r < 4; ++r) {
            int lrow = rt * 16 + rsub + r;
            float mv = (r == 0) ? mreg[rt].x : (r == 1) ? mreg[rt].y
                     : (r == 2) ? mreg[rt].z : mreg[rt].w;
            size_t grow = (size_t)row0 + lrow;
            #pragma unroll
            for (int ct = 0; ct < 4; ++ct) {
                int col = col0 + ct * 16 + lr;
                float y = fmaxf(acc[rt][ct][r] + bv[ct], 0.0f);
                int bo = (lrow * 512 + col * 2) ^ ((lrow & 7) << 4);
                float xv = bf2f(*(const unsigned short*)((const char*)lds_x + bo));
                float res = (mv != 0.0f) ? y : xv;
                __builtin_nontemporal_store(res, &out[grow * C_DIM + col]);
            }
        }
    }
}

extern "C" void kernel_launch(void* const* d_in, const int* in_sizes, int n_in,
                              void* d_out, int out_size, void* d_ws, size_t ws_size,
                              hipStream_t stream) {
    const float* x    = (const float*)d_in[0];
    const int*   mask = (const int*)d_in[1];
    const int*   fg   = (const int*)d_in[2];
    const float* W    = (const float*)d_in[3];
    const float* b    = (const float*)d_in[4];

    float* out   = (float*)d_out;
    float* m_out = out + (size_t)M_ROWS * C_DIM;      // output 1: m (N,B)
    unsigned short* Wbf = (unsigned short*)d_ws;      // 128 KB scratch

    prep_kernel<<<M_ROWS / 256, 256, 0, stream>>>(mask, fg, W, Wbf, m_out);
    mlp_kernel<<<M_ROWS / BM, 256, 0, stream>>>(x, Wbf, b, m_out, out);
}

// Round 5
// 61.842 us; speedup vs baseline: 1.2591x; 1.2591x over previous
//
#include <hip/hip_runtime.h>
#include <hip/hip_bf16.h>

#define N_TOK 16384
#define B_DIM 8
#define C_DIM 256
#define M_ROWS (N_TOK * B_DIM)   // 131072
#define BM 32

typedef __attribute__((ext_vector_type(8))) short short8;
typedef __attribute__((ext_vector_type(4))) float f32x4;

__device__ __forceinline__ unsigned short f2bf(float f) {
    union { float f; unsigned u; } v; v.f = f;
    unsigned r = v.u + 0x7fffu + ((v.u >> 16) & 1u);  // RNE
    return (unsigned short)(r >> 16);
}

__device__ __forceinline__ float bf2f(unsigned short h) {
    union { unsigned u; float f; } v; v.u = ((unsigned)h) << 16;
    return v.f;
}

// packed RNE f32x2 -> bf16x2 (low = a, high = b)
__device__ __forceinline__ unsigned cvt_pk(float a, float b) {
    unsigned r;
    asm("v_cvt_pk_bf16_f32 %0, %1, %2" : "=v"(r) : "v"(a), "v"(b));
    return r;
}

// Kernel A: m -> d_out tail; W fp32 -> bf16 in MFMA-fragment order.
// Fragment layout: for output-col-tile ctile (16 cols) and k-step k8 (K=32),
// lane L's short8 lives at Wf[((ctile*8 + k8)*64 + L)*8 .. +8), holding
// W[ctile*16 + (L&15)][k8*32 + (L>>4)*8 .. +8).
__global__ __launch_bounds__(256)
void prep_kernel(const int* __restrict__ mask, const int* __restrict__ fg,
                 const float* __restrict__ W, unsigned short* __restrict__ Wf,
                 float* __restrict__ m_out) {
    int i = blockIdx.x * 256 + threadIdx.x;
    if (i < C_DIM * C_DIM) {
        int d = i >> 8;            // W row = output col
        int c = i & 255;           // k
        int ctile = d >> 4;
        int k8    = c >> 5;
        int lane  = ((c >> 3) & 3) * 16 + (d & 15);
        int r     = c & 7;
        Wf[((ctile * 8 + k8) * 64 + lane) * 8 + r] = f2bf(W[i]);
    }
    if (i < M_ROWS) {
        int b = i & (B_DIM - 1);
        int n = i >> 3;
        m_out[i] = (fg[i] != 0) ? (1.0f - (float)mask[b * N_TOK + n]) : 0.0f;
    }
}

// Kernel B: 32-row tile per block (4096 blocks); bf16 x in 16 KB LDS
// (XOR-swizzled); W fragments coalesced from L2; fused relu+select epilogue.
__global__ __launch_bounds__(256, 6)
void mlp_kernel(const float* __restrict__ x, const unsigned short* __restrict__ Wf,
                const float* __restrict__ bias, const float* __restrict__ m,
                float* __restrict__ out) {
    __shared__ unsigned short lds_x[BM * C_DIM];  // 16 KB bf16

    const int t    = threadIdx.x;
    const int row0 = blockIdx.x * BM;

    // ---- Stage x tile (32 x 256 fp32 -> bf16 LDS), coalesced 32B/lane ----
    #pragma unroll
    for (int j = 0; j < 4; ++j) {
        int ci  = j * 256 + t;
        int row = ci >> 5;            // 0..31
        int cc  = (ci & 31) * 8;      // 0..248
        const float4* p = (const float4*)(x + (size_t)(row0 + row) * C_DIM + cc);
        float4 a0 = p[0];
        float4 a1 = p[1];
        int4 pk;
        pk.x = (int)cvt_pk(a0.x, a0.y);
        pk.y = (int)cvt_pk(a0.z, a0.w);
        pk.z = (int)cvt_pk(a1.x, a1.y);
        pk.w = (int)cvt_pk(a1.z, a1.w);
        int byte = (row * 512 + cc * 2) ^ ((row & 7) << 4);
        *(int4*)((char*)lds_x + byte) = pk;
    }
    __syncthreads();

    // ---- MFMA: 4 waves x 64 cols, 2(row) x 4(col) 16x16 tiles each ----
    const int lane = t & 63;
    const int wid  = t >> 6;
    const int col0 = wid * 64;
    const int lr   = lane & 15;
    const int kb   = (lane >> 4) * 8;
    const int rsub = (lane >> 4) * 4;   // C/D: row = (lane>>4)*4 + reg

    f32x4 acc[2][4];
    #pragma unroll
    for (int i = 0; i < 2; ++i)
        #pragma unroll
        for (int j = 0; j < 4; ++j) acc[i][j] = (f32x4){0.f, 0.f, 0.f, 0.f};

    // Wave's fragment base: ctile = wid*4 + ct
    const short8* wfb = (const short8*)Wf + (size_t)wid * 4 * 8 * 64 + lane;

    #pragma unroll
    for (int k8 = 0; k8 < 8; ++k8) {
        short8 bf[4];
        #pragma unroll
        for (int ct = 0; ct < 4; ++ct)
            bf[ct] = wfb[(ct * 8 + k8) * 64];     // 1 KB coalesced per wave
        short8 af[2];
        #pragma unroll
        for (int rt = 0; rt < 2; ++rt) {
            int row  = rt * 16 + lr;
            int byte = (row * 512 + (k8 * 32 + kb) * 2) ^ ((row & 7) << 4);
            af[rt] = *(const short8*)((const char*)lds_x + byte);
        }
        #pragma unroll
        for (int rt = 0; rt < 2; ++rt)
            #pragma unroll
            for (int ct = 0; ct < 4; ++ct)
                acc[rt][ct] = __builtin_amdgcn_mfma_f32_16x16x32_bf16(
                    af[rt], bf[ct], acc[rt][ct], 0, 0, 0);
    }

    // ---- Epilogue: relu(acc+b), select vs x (bf16 from LDS), store ----
    float bv[4];
    #pragma unroll
    for (int ct = 0; ct < 4; ++ct) bv[ct] = bias[col0 + ct * 16 + lr];

    #pragma unroll
    for (int rt = 0; rt < 2; ++rt) {
        float4 mreg = *(const float4*)(m + row0 + rt * 16 + rsub);
        #pragma unroll
        for (int r = 0; r < 4; ++r) {
            int lrow = rt * 16 + rsub + r;
            float mv = (r == 0) ? mreg.x : (r == 1) ? mreg.y
                     : (r == 2) ? mreg.z : mreg.w;
            size_t grow = (size_t)row0 + lrow;
            #pragma unroll
            for (int ct = 0; ct < 4; ++ct) {
                int col = col0 + ct * 16 + lr;
                float y = fmaxf(acc[rt][ct][r] + bv[ct], 0.0f);
                int bo = (lrow * 512 + col * 2) ^ ((lrow & 7) << 4);
                float xv = bf2f(*(const unsigned short*)((const char*)lds_x + bo));
                out[grow * C_DIM + col] = (mv != 0.0f) ? y : xv;
            }
        }
    }
}

extern "C" void kernel_launch(void* const* d_in, const int* in_sizes, int n_in,
                              void* d_out, int out_size, void* d_ws, size_t ws_size,
                              hipStream_t stream) {
    const float* x    = (const float*)d_in[0];
    const int*   mask = (const int*)d_in[1];
    const int*   fg   = (const int*)d_in[2];
    const float* W    = (const float*)d_in[3];
    const float* b    = (const float*)d_in[4];

    float* out   = (float*)d_out;
    float* m_out = out + (size_t)M_ROWS * C_DIM;      // output 1: m (N,B)
    unsigned short* Wf = (unsigned short*)d_ws;       // 128 KB fragment-order W

    prep_kernel<<<M_ROWS / 256, 256, 0, stream>>>(mask, fg, W, Wf, m_out);
    mlp_kernel<<<M_ROWS / BM, 256, 0, stream>>>(x, Wf, b, m_out, out);
}